// Round 13
// baseline (1101.411 us; speedup 1.0000x reference)
//
#include <hip/hip_runtime.h>
#include <hip/hip_cooperative_groups.h>

namespace cg = cooperative_groups;

#define N_NODES 100000
#define N_EDGES 1200000
#define N_GRAPHS 256
#define IN_C 5
#define HID_C 64
#define OUT_C 2

#define BSH 7
#define BNODES 128
#define NB ((N_NODES + BNODES - 1) / BNODES)        // 782
#define CSH 12
#define CAPB 4096
#define EPB 2048
#define NCHUNK ((N_EDGES + EPB - 1) / EPB)          // 586
#define GNPW 8
#define G1NPW 4
#define NGRP1 ((N_NODES + G1NPW - 1) / G1NPW)       // 25000
#define NGRP2 ((N_NODES + GNPW - 1) / GNPW)         // 12500
#define SENT N_NODES

typedef unsigned int uint32;

__device__ __forceinline__ uint32 f2bf(float f) {
    uint32 x = __float_as_uint(f);
    return (x + 0x7FFFu + ((x >> 16) & 1u)) >> 16;
}
__device__ __forceinline__ float bflo(uint32 r) { return __uint_as_float(r << 16); }
__device__ __forceinline__ float bfhi(uint32 r) { return __uint_as_float(r & 0xFFFF0000u); }

union SMem {
    struct { int h[NB]; } p1;
    struct {
        int hist[BNODES]; int tmp[BNODES]; int cur[BNODES];
        float sdv[BNODES];
        float sW1[IN_C * HID_C];
        float sx[BNODES * IN_C];
    } p2;
    struct {
        float sW2[HID_C * HID_C];
        float srow[4][HID_C];
    } p3;
};

__global__ void __launch_bounds__(256) mega(
        const int* __restrict__ src, const int* __restrict__ dst,
        const int* __restrict__ batch, const float* __restrict__ x,
        const float* __restrict__ W1, const float* __restrict__ b1,
        const float* __restrict__ W2, const float* __restrict__ b2,
        const float* __restrict__ Wfc, const float* __restrict__ bfc,
        float* __restrict__ out,
        int* __restrict__ bcnt, float* __restrict__ pooled,
        float* __restrict__ dinv, int* __restrict__ cnt, int* __restrict__ rs,
        int* __restrict__ pairs, int* __restrict__ csr,
        uint32* __restrict__ g1t, uint32* __restrict__ g2t) {
    __shared__ __align__(16) SMem sm;
    cg::grid_group grid = cg::this_grid();
    int tid = threadIdx.x;
    int bid = blockIdx.x;
    int gthreads = gridDim.x * 256;
    int gtid = bid * 256 + tid;

    // ===== phase 0: zero bcnt+pooled (contiguous 17408 words) + sentinel rows
    for (int i = gtid; i < 1024 + N_GRAPHS * HID_C; i += gthreads) {
        if (i < 1024) bcnt[i] = 0;
        else pooled[i - 1024] = 0.f;
    }
    if (gtid < 32) {
        g1t[(unsigned)SENT * 32 + gtid] = 0u;
        g2t[(unsigned)SENT * 32 + gtid] = 0u;
    }
    __threadfence();
    grid.sync();

    // ===== phase 1: bin edges into fixed-capacity bucket regions
    for (int c = bid; c < NCHUNK; c += gridDim.x) {
        __syncthreads();
        for (int i = tid; i < NB; i += 256) sm.p1.h[i] = 0;
        __syncthreads();
        int e0 = c * EPB;
        int e1 = e0 + EPB; if (e1 > N_EDGES) e1 = N_EDGES;
        for (int e = e0 + tid; e < e1; e += 256)
            atomicAdd(&sm.p1.h[dst[e] >> BSH], 1);
        __syncthreads();
        for (int i = tid; i < NB; i += 256)
            if (sm.p1.h[i]) sm.p1.h[i] = (i << CSH) + atomicAdd(&bcnt[i], sm.p1.h[i]);
        __syncthreads();
        for (int e = e0 + tid; e < e1; e += 256) {
            int d = dst[e];
            int pos = atomicAdd(&sm.p1.h[d >> BSH], 1);
            pairs[pos] = ((d & (BNODES - 1)) << 17) | src[e];
        }
    }
    __threadfence();
    grid.sync();

    // ===== phase 2: per-bucket counting sort -> padded CSR + rs/cnt/dinv + g1
    for (int b = bid; b < NB; b += gridDim.x) {
        __syncthreads();
        int base = b << BSH;
        if (tid < BNODES) sm.p2.hist[tid] = 0;
        for (int i = tid; i < IN_C * HID_C; i += 256) sm.p2.sW1[i] = W1[i];
        for (int i = tid; i < BNODES * IN_C; i += 256) {
            int gi = base * IN_C + i;
            sm.p2.sx[i] = (gi < N_NODES * IN_C) ? x[gi] : 0.f;
        }
        __syncthreads();
        int s = b << CSH;
        int n = bcnt[b];
        for (int i = tid; i < n; i += 256)
            atomicAdd(&sm.p2.hist[pairs[s + i] >> 17], 1);
        __syncthreads();
        int v = (tid < BNODES) ? sm.p2.hist[tid] : 0;
        int M = (v + 4) & ~3;               // padded count incl self, multiple of 4
        if (tid < BNODES) sm.p2.tmp[tid] = M;
        __syncthreads();
        for (int off = 1; off < BNODES; off <<= 1) {
            int a = (tid < BNODES && tid >= off) ? sm.p2.tmp[tid - off] : 0;
            __syncthreads();
            if (tid < BNODES) sm.p2.tmp[tid] += a;
            __syncthreads();
        }
        float dv_t = rsqrtf((float)v + 1.0f);
        if (tid < BNODES) {
            sm.p2.cur[tid] = sm.p2.tmp[tid] - M;
            sm.p2.sdv[tid] = dv_t;
            if (base + tid < N_NODES) {
                rs[base + tid] = s + sm.p2.tmp[tid] - M;
                cnt[base + tid] = M;
                dinv[base + tid] = dv_t;
            }
        }
        __syncthreads();
        for (int i = tid; i < n; i += 256) {
            int p = pairs[s + i];
            int pos = atomicAdd(&sm.p2.cur[p >> 17], 1);
            csr[s + pos] = p & 0x1FFFF;
        }
        __syncthreads();
        if (tid < BNODES && base + tid < N_NODES) {
            int p0 = sm.p2.cur[tid];
            int pe = sm.p2.tmp[tid];
            csr[s + p0] = base + tid;       // self-loop
            for (int j = p0 + 1; j < pe; ++j) csr[s + j] = SENT;
        }
        // g1 epilogue
        for (int idx = tid; idx < BNODES * 32; idx += 256) {
            int nl = idx >> 5, c2 = idx & 31;
            int node = base + nl;
            if (node >= N_NODES) break;
            float s0 = 0.f, s1 = 0.f;
#pragma unroll
            for (int k = 0; k < IN_C; ++k) {
                float xv = sm.p2.sx[nl * IN_C + k];
                float2 wv = *(const float2*)&sm.p2.sW1[k * HID_C + 2 * c2];
                s0 += xv * wv.x;
                s1 += xv * wv.y;
            }
            float dv = sm.p2.sdv[nl];
            g1t[(unsigned)node * 32 + c2] = (f2bf(s1 * dv) << 16) | f2bf(s0 * dv);
        }
    }
    __threadfence();
    grid.sync();

    // ===== phase 3: gather layer-1 + relu + g2 matmul
    for (int i = tid; i < HID_C * HID_C; i += 256) sm.p3.sW2[i] = W2[i];
    __syncthreads();
    {
        int w = tid >> 6;
        int lane = tid & 63;
        int q = lane >> 4;
        int c4 = lane & 15;
        int half = lane >> 5;
        int c2 = lane & 31;
        int totw = gridDim.x * 4;
        int gw = bid * 4 + w;
        float4 bia = *(const float4*)&b1[4 * c4];
        for (int grp = gw; grp < NGRP1; grp += totw) {
            int n0 = grp * G1NPW;
            int n1 = n0 + G1NPW; if (n1 > N_NODES) n1 = N_NODES;
            for (int v = n0; v < n1; ++v) {
                int k0 = rs[v];
                int M = cnt[v];
                float s0 = 0.f, s1 = 0.f, s2 = 0.f, s3 = 0.f;
                int i = 0;
                for (; i + 8 <= M; i += 8) {
                    int4 ua = *(const int4*)&csr[k0 + i];
                    int4 ub = *(const int4*)&csr[k0 + i + 4];
                    int a0 = (q == 0) ? ua.x : (q == 1) ? ua.y : (q == 2) ? ua.z : ua.w;
                    int a1 = (q == 0) ? ub.x : (q == 1) ? ub.y : (q == 2) ? ub.z : ub.w;
                    uint2 r0 = *(const uint2*)&g1t[(unsigned)a0 * 32 + 2 * c4];
                    uint2 r1 = *(const uint2*)&g1t[(unsigned)a1 * 32 + 2 * c4];
                    s0 += bflo(r0.x) + bflo(r1.x);
                    s1 += bfhi(r0.x) + bfhi(r1.x);
                    s2 += bflo(r0.y) + bflo(r1.y);
                    s3 += bfhi(r0.y) + bfhi(r1.y);
                }
                if (i < M) {
                    int4 ua = *(const int4*)&csr[k0 + i];
                    int a0 = (q == 0) ? ua.x : (q == 1) ? ua.y : (q == 2) ? ua.z : ua.w;
                    uint2 r0 = *(const uint2*)&g1t[(unsigned)a0 * 32 + 2 * c4];
                    s0 += bflo(r0.x); s1 += bfhi(r0.x); s2 += bflo(r0.y); s3 += bfhi(r0.y);
                }
                s0 += __shfl_xor(s0, 16); s1 += __shfl_xor(s1, 16);
                s2 += __shfl_xor(s2, 16); s3 += __shfl_xor(s3, 16);
                s0 += __shfl_xor(s0, 32); s1 += __shfl_xor(s1, 32);
                s2 += __shfl_xor(s2, 32); s3 += __shfl_xor(s3, 32);
                float dv = dinv[v];
                float o0 = fmaxf(s0 * dv + bia.x, 0.f);
                float o1 = fmaxf(s1 * dv + bia.y, 0.f);
                float o2 = fmaxf(s2 * dv + bia.z, 0.f);
                float o3 = fmaxf(s3 * dv + bia.w, 0.f);
                if (lane < 16) *(float4*)&sm.p3.srow[w][4 * lane] = make_float4(o0, o1, o2, o3);
                int kb = half << 5;
                float a0 = 0.f, a1 = 0.f;
#pragma unroll 8
                for (int j = 0; j < 32; ++j) {
                    float hv = sm.p3.srow[w][kb + j];
                    float2 wvv = *(const float2*)&sm.p3.sW2[(kb + j) * HID_C + 2 * c2];
                    a0 += hv * wvv.x;
                    a1 += hv * wvv.y;
                }
                a0 += __shfl_xor(a0, 32);
                a1 += __shfl_xor(a1, 32);
                if (half == 0)
                    g2t[(unsigned)v * 32 + c2] = (f2bf(a1 * dv) << 16) | f2bf(a0 * dv);
            }
        }
    }
    __threadfence();
    grid.sync();

    // ===== phase 4: gather layer-2 + relu + mean-pool accumulate
    {
        int w = tid >> 6;
        int lane = tid & 63;
        int q = lane >> 4;
        int c4 = lane & 15;
        int totw = gridDim.x * 4;
        int gw = bid * 4 + w;
        float4 bia = *(const float4*)&b2[4 * c4];
        for (int grp = gw; grp < NGRP2; grp += totw) {
            int n0 = grp * GNPW;
            int n1 = n0 + GNPW; if (n1 > N_NODES) n1 = N_NODES;
            float p0 = 0.f, p1 = 0.f, p2 = 0.f, p3 = 0.f;
            int curg = batch[n0];
            for (int v = n0; v < n1; ++v) {
                int k0 = rs[v];
                int M = cnt[v];
                float s0 = 0.f, s1 = 0.f, s2 = 0.f, s3 = 0.f;
                int i = 0;
                for (; i + 8 <= M; i += 8) {
                    int4 ua = *(const int4*)&csr[k0 + i];
                    int4 ub = *(const int4*)&csr[k0 + i + 4];
                    int a0 = (q == 0) ? ua.x : (q == 1) ? ua.y : (q == 2) ? ua.z : ua.w;
                    int a1 = (q == 0) ? ub.x : (q == 1) ? ub.y : (q == 2) ? ub.z : ub.w;
                    uint2 r0 = *(const uint2*)&g2t[(unsigned)a0 * 32 + 2 * c4];
                    uint2 r1 = *(const uint2*)&g2t[(unsigned)a1 * 32 + 2 * c4];
                    s0 += bflo(r0.x) + bflo(r1.x);
                    s1 += bfhi(r0.x) + bfhi(r1.x);
                    s2 += bflo(r0.y) + bflo(r1.y);
                    s3 += bfhi(r0.y) + bfhi(r1.y);
                }
                if (i < M) {
                    int4 ua = *(const int4*)&csr[k0 + i];
                    int a0 = (q == 0) ? ua.x : (q == 1) ? ua.y : (q == 2) ? ua.z : ua.w;
                    uint2 r0 = *(const uint2*)&g2t[(unsigned)a0 * 32 + 2 * c4];
                    s0 += bflo(r0.x); s1 += bfhi(r0.x); s2 += bflo(r0.y); s3 += bfhi(r0.y);
                }
                s0 += __shfl_xor(s0, 16); s1 += __shfl_xor(s1, 16);
                s2 += __shfl_xor(s2, 16); s3 += __shfl_xor(s3, 16);
                s0 += __shfl_xor(s0, 32); s1 += __shfl_xor(s1, 32);
                s2 += __shfl_xor(s2, 32); s3 += __shfl_xor(s3, 32);
                float dv = dinv[v];
                float o0 = fmaxf(s0 * dv + bia.x, 0.f);
                float o1 = fmaxf(s1 * dv + bia.y, 0.f);
                float o2 = fmaxf(s2 * dv + bia.z, 0.f);
                float o3 = fmaxf(s3 * dv + bia.w, 0.f);
                int gg = batch[v];
                if (gg != curg) {
                    if (lane < 16) {
                        atomicAdd(&pooled[curg * HID_C + 4 * c4 + 0], p0);
                        atomicAdd(&pooled[curg * HID_C + 4 * c4 + 1], p1);
                        atomicAdd(&pooled[curg * HID_C + 4 * c4 + 2], p2);
                        atomicAdd(&pooled[curg * HID_C + 4 * c4 + 3], p3);
                    }
                    p0 = p1 = p2 = p3 = 0.f; curg = gg;
                }
                p0 += o0; p1 += o1; p2 += o2; p3 += o3;
            }
            if (lane < 16) {
                atomicAdd(&pooled[curg * HID_C + 4 * c4 + 0], p0);
                atomicAdd(&pooled[curg * HID_C + 4 * c4 + 1], p1);
                atomicAdd(&pooled[curg * HID_C + 4 * c4 + 2], p2);
                atomicAdd(&pooled[curg * HID_C + 4 * c4 + 3], p3);
            }
        }
    }
    __threadfence();
    grid.sync();

    // ===== phase 5: mean + FC (blocks 0..255, wave 0)
    if (bid < N_GRAPHS && tid < 64) {
        int g = bid;
        int c = tid;
        int lo = 0, hi = N_NODES;
        while (lo < hi) { int mid = (lo + hi) >> 1; if (batch[mid] < g) lo = mid + 1; else hi = mid; }
        int start = lo;
        hi = N_NODES;
        while (lo < hi) { int mid = (lo + hi) >> 1; if (batch[mid] < g + 1) lo = mid + 1; else hi = mid; }
        int n = lo - start;
        float pv = pooled[g * HID_C + c] / (float)(n > 0 ? n : 1);
        float o0 = pv * Wfc[c * OUT_C + 0];
        float o1 = pv * Wfc[c * OUT_C + 1];
#pragma unroll
        for (int off = 32; off > 0; off >>= 1) {
            o0 += __shfl_down(o0, off);
            o1 += __shfl_down(o1, off);
        }
        if (c == 0) {
            out[g * OUT_C + 0] = o0 + bfc[0];
            out[g * OUT_C + 1] = o1 + bfc[1];
        }
    }
}

extern "C" void kernel_launch(void* const* d_in, const int* in_sizes, int n_in,
                              void* d_out, int out_size, void* d_ws, size_t ws_size,
                              hipStream_t stream) {
    const float* x    = (const float*)d_in[0];
    const int*   ei   = (const int*)d_in[1];
    const int*   src  = ei;
    const int*   dst  = ei + N_EDGES;
    const int*   batch= (const int*)d_in[2];
    const float* W1   = (const float*)d_in[3];
    const float* b1   = (const float*)d_in[4];
    const float* W2   = (const float*)d_in[5];
    const float* b2   = (const float*)d_in[6];
    const float* Wfc  = (const float*)d_in[7];
    const float* bfc  = (const float*)d_in[8];
    float* out = (float*)d_out;

    // workspace layout (4B elems); bcnt+pooled adjacent (zeroed in phase 0)
    float*  ws     = (float*)d_ws;
    int*    bcnt   = (int*)ws;                    // 1024
    float*  pooled = ws + 1024;                   // 16384
    float*  dinv   = pooled + 16384;              // 100352
    int*    cnt    = (int*)(dinv + 100352);       // 100352
    int*    rs     = cnt + 100352;                // 100352
    int*    pairs  = rs + 100352;                 // NB*CAPB
    int*    csr    = pairs + (NB * CAPB);         // NB*CAPB
    uint32* g1tab  = (uint32*)(csr + (NB * CAPB));// (N+1)*32
    uint32* g2tab  = g1tab + (N_NODES + 1) * 32;  // (N+1)*32

    int nb = 0;
    hipOccupancyMaxActiveBlocksPerMultiprocessor(&nb, mega, 256, 0);
    if (nb < 1) nb = 1;
    if (nb > 8) nb = 8;
    int grid = nb * 256;                          // 256 CUs on MI355X

    void* args[] = {
        (void*)&src, (void*)&dst, (void*)&batch, (void*)&x,
        (void*)&W1, (void*)&b1, (void*)&W2, (void*)&b2,
        (void*)&Wfc, (void*)&bfc, (void*)&out,
        (void*)&bcnt, (void*)&pooled, (void*)&dinv, (void*)&cnt, (void*)&rs,
        (void*)&pairs, (void*)&csr, (void*)&g1tab, (void*)&g2tab
    };
    hipLaunchCooperativeKernel((void*)mega, dim3(grid), dim3(256), args, 0, stream);
}

// Round 14
// 220.557 us; speedup vs baseline: 4.9938x; 4.9938x over previous
//
#include <hip/hip_runtime.h>

#define N_NODES 100000
#define N_EDGES 1200000
#define N_GRAPHS 256
#define IN_C 5
#define HID_C 64
#define OUT_C 2

#define BSH 7
#define BNODES 128
#define NB ((N_NODES + BNODES - 1) / BNODES)        // 782
#define CAPB 2048                                   // fixed bucket capacity (E=1534, sigma=39)
#define EPB 2048                                    // edges per block (binning)
#define NBLK_E ((N_EDGES + EPB - 1) / EPB)          // 586
#define GNPW 8                                      // nodes per wave in fused gather2+pool
#define G1NPW 4                                     // nodes per wave in fused gather1+g2

typedef unsigned int uint32;

// fp32 -> bf16 round-to-nearest-even (returns 16-bit pattern)
__device__ __forceinline__ uint32 f2bf(float f) {
    uint32 x = __float_as_uint(f);
    return (x + 0x7FFFu + ((x >> 16) & 1u)) >> 16;
}
__device__ __forceinline__ float bflo(uint32 r) { return __uint_as_float(r << 16); }
__device__ __forceinline__ float bfhi(uint32 r) { return __uint_as_float(r & 0xFFFF0000u); }

// ---- bin edges into fixed-capacity bucket regions, packed (dst_local<<17)|src.
// Blocks 0..63 also zero the pooled accumulator (consumed 2 dispatches later).
__global__ void k_bscatter(const int* __restrict__ src, const int* __restrict__ dst,
                           int* __restrict__ bcnt, int* __restrict__ pairs,
                           float* __restrict__ pooled) {
    __shared__ int h[NB];
    if (blockIdx.x < (N_GRAPHS * HID_C) / 256)
        pooled[blockIdx.x * 256 + threadIdx.x] = 0.f;
    for (int i = threadIdx.x; i < NB; i += blockDim.x) h[i] = 0;
    __syncthreads();
    int e0 = blockIdx.x * EPB;
    int e1 = e0 + EPB; if (e1 > N_EDGES) e1 = N_EDGES;
    for (int e = e0 + threadIdx.x; e < e1; e += blockDim.x)
        atomicAdd(&h[dst[e] >> BSH], 1);
    __syncthreads();
    for (int i = threadIdx.x; i < NB; i += blockDim.x)
        if (h[i]) h[i] = (i << 11) + atomicAdd(&bcnt[i], h[i]);
    __syncthreads();
    for (int e = e0 + threadIdx.x; e < e1; e += blockDim.x) {
        int d = dst[e];
        int pos = atomicAdd(&h[d >> BSH], 1);
        pairs[pos] = ((d & (BNODES - 1)) << 17) | src[e];
    }
}

// ---- per-bucket counting sort -> CSR + rs/cnt/dinv, FUSED with g1 epilogue:
// g1[node] = bf16x2((x[node] @ W1) * dinv[node]) for the block's 128 nodes.
__global__ void k_bsort_g1(const int* __restrict__ pairs, const int* __restrict__ bcnt,
                           const float* __restrict__ x, const float* __restrict__ W1,
                           int* __restrict__ csr, int* __restrict__ rs,
                           int* __restrict__ cnt, float* __restrict__ dinv,
                           uint32* __restrict__ g) {
    __shared__ int hist[BNODES];
    __shared__ int tmp[BNODES];
    __shared__ int cur[BNODES];
    __shared__ float sdv[BNODES];
    __shared__ __align__(16) float sW1[IN_C * HID_C];   // 1.25 KB
    __shared__ float sx[BNODES * IN_C];                 // 2.5 KB
    int b = blockIdx.x;
    int t = threadIdx.x;
    int base = b << BSH;
    if (t < BNODES) hist[t] = 0;
    for (int i = t; i < IN_C * HID_C; i += 256) sW1[i] = W1[i];
    for (int i = t; i < BNODES * IN_C; i += 256) {
        int gi = base * IN_C + i;
        sx[i] = (gi < N_NODES * IN_C) ? x[gi] : 0.f;
    }
    __syncthreads();
    int s = b << 11;            // fixed bucket start
    int n = bcnt[b];
    for (int i = t; i < n; i += 256)
        atomicAdd(&hist[pairs[s + i] >> 17], 1);
    __syncthreads();
    int v = (t < BNODES) ? hist[t] : 0;
    if (t < BNODES) tmp[t] = v;
    __syncthreads();
    for (int off = 1; off < BNODES; off <<= 1) {
        int a = (t < BNODES && t >= off) ? tmp[t - off] : 0;
        __syncthreads();
        if (t < BNODES) tmp[t] += a;
        __syncthreads();
    }
    float dv_t = rsqrtf((float)v + 1.0f);
    if (t < BNODES) {
        cur[t] = tmp[t] - v;
        sdv[t] = dv_t;
        if (base + t < N_NODES) {
            rs[base + t] = s + tmp[t] - v;
            cnt[base + t] = v;
            dinv[base + t] = dv_t;
        }
    }
    __syncthreads();
    for (int i = t; i < n; i += 256) {
        int p = pairs[s + i];
        int pos = atomicAdd(&cur[p >> 17], 1);
        csr[s + pos] = p & 0x1FFFF;
    }
    // ---- g1 epilogue: 128 nodes x 32 channel-pairs ----
    for (int idx = t; idx < BNODES * 32; idx += 256) {
        int nl = idx >> 5, c2 = idx & 31;
        int node = base + nl;
        if (node >= N_NODES) break;
        float s0 = 0.f, s1 = 0.f;
#pragma unroll
        for (int k = 0; k < IN_C; ++k) {
            float xv = sx[nl * IN_C + k];
            float2 wv = *(const float2*)&sW1[k * HID_C + 2 * c2];
            s0 += xv * wv.x;
            s1 += xv * wv.y;
        }
        float dv = sdv[nl];
        g[(unsigned)node * 32 + c2] = (f2bf(s1 * dv) << 16) | f2bf(s0 * dv);
    }
}

// ---- fused gather layer-1 + relu + g2 matmul: reads g1tab, writes g2tab.
// One wave handles G1NPW nodes; h1 row bounces through per-wave LDS, W2 in LDS.
__global__ void __launch_bounds__(256) k_gather_g2(
        const uint32* __restrict__ g1t, const int* __restrict__ csr,
        const int* __restrict__ rs, const int* __restrict__ cnt,
        const float* __restrict__ dinv, const float* __restrict__ b1,
        const float* __restrict__ W2, uint32* __restrict__ g2t) {
    __shared__ __align__(16) float sW2[HID_C * HID_C];  // 16 KB
    __shared__ float srow[4][HID_C];                    // 1 KB (per-wave row buffer)
    int tid = threadIdx.x;
    for (int i = tid; i < HID_C * HID_C; i += 256) sW2[i] = W2[i];
    __syncthreads();
    int w = tid >> 6;
    int wv = __builtin_amdgcn_readfirstlane(blockIdx.x * 4 + w);
    int n0 = wv * G1NPW;
    if (n0 >= N_NODES) return;
    int n1 = n0 + G1NPW; if (n1 > N_NODES) n1 = N_NODES;
    int lane = tid & 63;
    int half = lane >> 5;
    int c2 = lane & 31;
    float bias0 = b1[2 * c2], bias1 = b1[2 * c2 + 1];
    for (int v = n0; v < n1; ++v) {
        int k0 = rs[v];
        int n = cnt[v];
        float s0 = 0.f, s1 = 0.f;
        if (half == 0) {          // self-loop
            uint32 r = g1t[(unsigned)v * 32 + c2];
            s0 = bflo(r); s1 = bfhi(r);
        }
        int i = 0;
        for (; i + 7 < n; i += 8) {
            int u0 = csr[k0 + i + 0], u1 = csr[k0 + i + 1];
            int u2 = csr[k0 + i + 2], u3 = csr[k0 + i + 3];
            int u4 = csr[k0 + i + 4], u5 = csr[k0 + i + 5];
            int u6 = csr[k0 + i + 6], u7 = csr[k0 + i + 7];
            int a0 = half ? u1 : u0;
            int a1 = half ? u3 : u2;
            int a2 = half ? u5 : u4;
            int a3 = half ? u7 : u6;
            uint32 r0 = g1t[(unsigned)a0 * 32 + c2];
            uint32 r1 = g1t[(unsigned)a1 * 32 + c2];
            uint32 r2 = g1t[(unsigned)a2 * 32 + c2];
            uint32 r3 = g1t[(unsigned)a3 * 32 + c2];
            s0 += (bflo(r0) + bflo(r1)) + (bflo(r2) + bflo(r3));
            s1 += (bfhi(r0) + bfhi(r1)) + (bfhi(r2) + bfhi(r3));
        }
        for (; i + 1 < n; i += 2) {
            int u0 = csr[k0 + i], u1 = csr[k0 + i + 1];
            int a = half ? u1 : u0;
            uint32 r = g1t[(unsigned)a * 32 + c2];
            s0 += bflo(r); s1 += bfhi(r);
        }
        if (i < n && half == 0) {
            uint32 r = g1t[(unsigned)csr[k0 + i] * 32 + c2];
            s0 += bflo(r); s1 += bfhi(r);
        }
        s0 += __shfl_xor(s0, 32);
        s1 += __shfl_xor(s1, 32);
        float dv = dinv[v];
        float o0 = fmaxf(s0 * dv + bias0, 0.f);   // h1[v][2c2]
        float o1 = fmaxf(s1 * dv + bias1, 0.f);   // h1[v][2c2+1]
        if (half == 0) *(float2*)&srow[w][2 * c2] = make_float2(o0, o1);
        // g2 = (h1 @ W2) * dinv: halves split the k range, then combine
        int kb = half << 5;
        float a0 = 0.f, a1 = 0.f;
#pragma unroll 8
        for (int j = 0; j < 32; ++j) {
            float hv = srow[w][kb + j];
            float2 wvv = *(const float2*)&sW2[(kb + j) * HID_C + 2 * c2];
            a0 += hv * wvv.x;
            a1 += hv * wvv.y;
        }
        a0 += __shfl_xor(a0, 32);
        a1 += __shfl_xor(a1, 32);
        if (half == 0)
            g2t[(unsigned)v * 32 + c2] = (f2bf(a1 * dv) << 16) | f2bf(a0 * dv);
    }
}

// ---- gather layer 2 fused with relu + mean-pool accumulate
__global__ void k_gather2p(const uint32* __restrict__ g, const int* __restrict__ csr,
                           const int* __restrict__ rs, const int* __restrict__ cnt,
                           const float* __restrict__ dinv, const float* __restrict__ b,
                           const int* __restrict__ batch, float* __restrict__ pooled) {
    int wv = __builtin_amdgcn_readfirstlane(
        blockIdx.x * (blockDim.x >> 6) + (threadIdx.x >> 6));
    int n0 = wv * GNPW;
    if (n0 >= N_NODES) return;
    int n1 = n0 + GNPW; if (n1 > N_NODES) n1 = N_NODES;
    int lane = threadIdx.x & 63;
    int half = lane >> 5;
    int c2 = lane & 31;
    float bias0 = b[2 * c2], bias1 = b[2 * c2 + 1];
    float p0 = 0.f, p1 = 0.f;
    int curg = batch[n0];
    for (int v = n0; v < n1; ++v) {
        int k0 = rs[v];
        int n = cnt[v];
        float s0 = 0.f, s1 = 0.f;
        if (half == 0) {
            uint32 r = g[(unsigned)v * 32 + c2];
            s0 = bflo(r); s1 = bfhi(r);
        }
        int i = 0;
        for (; i + 7 < n; i += 8) {
            int u0 = csr[k0 + i + 0], u1 = csr[k0 + i + 1];
            int u2 = csr[k0 + i + 2], u3 = csr[k0 + i + 3];
            int u4 = csr[k0 + i + 4], u5 = csr[k0 + i + 5];
            int u6 = csr[k0 + i + 6], u7 = csr[k0 + i + 7];
            int a0 = half ? u1 : u0;
            int a1 = half ? u3 : u2;
            int a2 = half ? u5 : u4;
            int a3 = half ? u7 : u6;
            uint32 r0 = g[(unsigned)a0 * 32 + c2];
            uint32 r1 = g[(unsigned)a1 * 32 + c2];
            uint32 r2 = g[(unsigned)a2 * 32 + c2];
            uint32 r3 = g[(unsigned)a3 * 32 + c2];
            s0 += (bflo(r0) + bflo(r1)) + (bflo(r2) + bflo(r3));
            s1 += (bfhi(r0) + bfhi(r1)) + (bfhi(r2) + bfhi(r3));
        }
        for (; i + 1 < n; i += 2) {
            int u0 = csr[k0 + i], u1 = csr[k0 + i + 1];
            int a = half ? u1 : u0;
            uint32 r = g[(unsigned)a * 32 + c2];
            s0 += bflo(r); s1 += bfhi(r);
        }
        if (i < n && half == 0) {
            uint32 r = g[(unsigned)csr[k0 + i] * 32 + c2];
            s0 += bflo(r); s1 += bfhi(r);
        }
        s0 += __shfl_xor(s0, 32);
        s1 += __shfl_xor(s1, 32);
        float dv = dinv[v];
        float o0 = fmaxf(s0 * dv + bias0, 0.f);
        float o1 = fmaxf(s1 * dv + bias1, 0.f);
        int gg = batch[v];
        if (gg != curg) {
            if (half == 0) {
                atomicAdd(&pooled[curg * HID_C + 2 * c2], p0);
                atomicAdd(&pooled[curg * HID_C + 2 * c2 + 1], p1);
            }
            p0 = 0.f; p1 = 0.f; curg = gg;
        }
        p0 += o0; p1 += o1;
    }
    if (half == 0) {
        atomicAdd(&pooled[curg * HID_C + 2 * c2], p0);
        atomicAdd(&pooled[curg * HID_C + 2 * c2 + 1], p1);
    }
}

// ---- mean + FC; one block (64 thr) per graph
__global__ void k_fc(const float* __restrict__ pooled, const int* __restrict__ batch,
                     const float* __restrict__ Wfc, const float* __restrict__ bfc,
                     float* __restrict__ out) {
    int g = blockIdx.x;
    int c = threadIdx.x;
    int lo = 0, hi = N_NODES;
    while (lo < hi) { int mid = (lo + hi) >> 1; if (batch[mid] < g) lo = mid + 1; else hi = mid; }
    int start = lo;
    hi = N_NODES;
    while (lo < hi) { int mid = (lo + hi) >> 1; if (batch[mid] < g + 1) lo = mid + 1; else hi = mid; }
    int n = lo - start;
    float pv = pooled[g * HID_C + c] / (float)(n > 0 ? n : 1);
    float o0 = pv * Wfc[c * OUT_C + 0];
    float o1 = pv * Wfc[c * OUT_C + 1];
#pragma unroll
    for (int off = 32; off > 0; off >>= 1) {
        o0 += __shfl_down(o0, off);
        o1 += __shfl_down(o1, off);
    }
    if (c == 0) {
        out[g * OUT_C + 0] = o0 + bfc[0];
        out[g * OUT_C + 1] = o1 + bfc[1];
    }
}

extern "C" void kernel_launch(void* const* d_in, const int* in_sizes, int n_in,
                              void* d_out, int out_size, void* d_ws, size_t ws_size,
                              hipStream_t stream) {
    const float* x    = (const float*)d_in[0];
    const int*   ei   = (const int*)d_in[1];
    const int*   src  = ei;
    const int*   dst  = ei + N_EDGES;
    const int*   batch= (const int*)d_in[2];
    const float* W1   = (const float*)d_in[3];
    const float* b1   = (const float*)d_in[4];
    const float* W2   = (const float*)d_in[5];
    const float* b2   = (const float*)d_in[6];
    const float* Wfc  = (const float*)d_in[7];
    const float* bfc  = (const float*)d_in[8];
    float* out = (float*)d_out;

    // workspace layout (4B elems)
    float*  ws     = (float*)d_ws;
    int*    bcnt   = (int*)ws;                    // 1024
    float*  pooled = ws + 1024;                   // 16384 (zeroed by k_bscatter)
    float*  dinv   = pooled + 16384;              // 100352
    int*    cnt    = (int*)(dinv + 100352);       // 100352
    int*    rs     = cnt + 100352;                // 100352
    int*    pairs  = rs + 100352;                 // NB*CAPB = 1601536
    int*    csr    = pairs + (NB * CAPB);         // 1601536
    uint32* g1tab  = (uint32*)(csr + (NB * CAPB));// N*32 uint32 = 12.8 MB
    uint32* g2tab  = g1tab + N_NODES * 32;        // N*32 uint32 = 12.8 MB

    hipMemsetAsync(bcnt, 0, 1024 * sizeof(int), stream);

    // ---- CSR build + g1 (fused) ----
    k_bscatter<<<NBLK_E, 256, 0, stream>>>(src, dst, bcnt, pairs, pooled);
    k_bsort_g1<<<NB, 256, 0, stream>>>(pairs, bcnt, x, W1, csr, rs, cnt, dinv, g1tab);

    // ---- layer-1 gather + relu + g2 matmul (fused; h1 never hits global) ----
    {
        int waves = (N_NODES + G1NPW - 1) / G1NPW;   // 25000
        int blocks = (waves + 3) / 4;                // 6250
        k_gather_g2<<<blocks, 256, 0, stream>>>(g1tab, csr, rs, cnt, dinv, b1, W2, g2tab);
    }

    // ---- layer-2 gather + relu + mean-pool (fused) ----
    {
        int waves = (N_NODES + GNPW - 1) / GNPW;     // 12500
        int blocks = (waves + 3) / 4;                // 3125
        k_gather2p<<<blocks, 256, 0, stream>>>(g2tab, csr, rs, cnt, dinv, b2, batch, pooled);
    }

    // ---- FC ----
    k_fc<<<N_GRAPHS, 64, 0, stream>>>(pooled, batch, Wfc, bfc, out);
}